// Round 2
// baseline (14452.380 us; speedup 1.0000x reference)
//
#include <hip/hip_runtime.h>
#include <hip/hip_bf16.h>

#define NENT 40000
#define NREL 20
#define DIM 128
#define NBASIS 8
#define NTILE 625              // 40000 / 64 dst-tiles
#define NBIN (NREL * NTILE)    // 12500 (rel, dst-tile) bins

// W[r] = sum_b comp[r,b] * basis[b]  for both layers at once
__global__ void k_weights(const float* __restrict__ comp1, const float* __restrict__ basis1,
                          const float* __restrict__ comp2, const float* __restrict__ basis2,
                          float* __restrict__ W1, float* __restrict__ W2) {
    int idx = blockIdx.x * 256 + threadIdx.x;
    if (idx >= NREL * DIM * DIM) return;
    int r = idx >> 14;
    int io = idx & 16383;
    float s1 = 0.f, s2 = 0.f;
#pragma unroll
    for (int b = 0; b < NBASIS; ++b) {
        s1 += comp1[r * NBASIS + b] * basis1[b * 16384 + io];
        s2 += comp2[r * NBASIS + b] * basis2[b * 16384 + io];
    }
    W1[idx] = s1;
    W2[idx] = s2;
}

// histogram over (rel, dst-tile) bins + in-degree (all edges, any rel)
__global__ void k_hist(const int* __restrict__ et, const int* __restrict__ dst, int E,
                       int* __restrict__ hist, float* __restrict__ deg) {
    int e = blockIdx.x * 256 + threadIdx.x;
    if (e >= E) return;
    int d = dst[e];
    int bin = et[e] * NTILE + (d >> 6);
    atomicAdd(&hist[bin], 1);
    atomicAdd(&deg[d], 1.0f);
}

// exclusive scan over 12500 bins, single block
__global__ void k_scan(const int* __restrict__ hist, int* __restrict__ offs,
                       int* __restrict__ cursor) {
    __shared__ int ps[256];
    int t = threadIdx.x;
    const int chunk = (NBIN + 255) / 256;   // 49
    int lo = t * chunk, hi = min(NBIN, lo + chunk);
    int s = 0;
    for (int i = lo; i < hi; ++i) s += hist[i];
    ps[t] = s;
    __syncthreads();
    for (int off = 1; off < 256; off <<= 1) {
        int v = (t >= off) ? ps[t - off] : 0;
        __syncthreads();
        ps[t] += v;
        __syncthreads();
    }
    int run = (t == 0) ? 0 : ps[t - 1];
    for (int i = lo; i < hi; ++i) {
        offs[i] = run;
        cursor[i] = run;
        run += hist[i];
    }
    if (t == 255) offs[NBIN] = run;
}

// counting-sort scatter into bin order (order within bin irrelevant)
__global__ void k_scatter(const int* __restrict__ et, const int* __restrict__ dst, int E,
                          int* __restrict__ cursor, int* __restrict__ sorted) {
    int e = blockIdx.x * 256 + threadIdx.x;
    if (e >= E) return;
    int bin = et[e] * NTILE + (dst[e] >> 6);
    int pos = atomicAdd(&cursor[bin], 1);
    sorted[pos] = e;
}

// Fused RGCN layer: one block owns 64 dst rows. For each relation:
// build S[64][128] (sum of x[src] per dst) in LDS via gathered rows + LDS
// atomics, then acc += S @ W_r (registers). Then acc/deg, fused root GEMM,
// bias, optional tanh, single coalesced write. Zero global atomics.
__global__ __launch_bounds__(256) void k_rgcn_tile(
    const float* __restrict__ x, const float* __restrict__ W,
    const float* __restrict__ root, const float* __restrict__ bias,
    const int* __restrict__ sorted, const int* __restrict__ offs,
    const int* __restrict__ src, const int* __restrict__ dstA,
    const float* __restrict__ deg, float* __restrict__ out, int act) {
    __shared__ __align__(16) float Ss[64][132];   // +4 pad: 2-way bank alias only
    int tile = blockIdx.x;
    int t0 = tile * 64;
    int t = threadIdx.x;
    int e = t >> 2;              // output row 0..63
    int ob = (t & 3) * 32;       // output col base
    float acc[32];
#pragma unroll
    for (int j = 0; j < 32; ++j) acc[j] = 0.f;

    for (int r = 0; r < NREL; ++r) {
        // zero S tile (only the [64][0..128) region is read)
#pragma unroll
        for (int p = 0; p < 8; ++p) {
            int row = (t >> 5) + p * 8;
            *(float4*)(&Ss[row][(t & 31) * 4]) = make_float4(0.f, 0.f, 0.f, 0.f);
        }
        __syncthreads();

        int beg = offs[r * NTILE + tile];
        int end = offs[r * NTILE + tile + 1];
        // 8 edges in flight; 32 threads per edge (one float4 each)
        for (int ei = beg + (t >> 5); ei < end; ei += 8) {
            int eid = sorted[ei];
            int s = src[eid];
            int d = dstA[eid] - t0;
            int c4 = t & 31;
            float4 v = *(const float4*)(x + (long)s * DIM + c4 * 4);
            atomicAdd(&Ss[d][c4 * 4 + 0], v.x);
            atomicAdd(&Ss[d][c4 * 4 + 1], v.y);
            atomicAdd(&Ss[d][c4 * 4 + 2], v.z);
            atomicAdd(&Ss[d][c4 * 4 + 3], v.w);
        }
        __syncthreads();

        if (end > beg) {   // block-uniform
            const float4* Wr = (const float4*)(W + (long)r * DIM * DIM);
            for (int i = 0; i < DIM; ++i) {
                float xi = Ss[e][i];
                const float4* wrow = Wr + i * (DIM / 4) + (ob >> 2);
#pragma unroll
                for (int j4 = 0; j4 < 8; ++j4) {
                    float4 w = wrow[j4];
                    acc[j4 * 4 + 0] += xi * w.x;
                    acc[j4 * 4 + 1] += xi * w.y;
                    acc[j4 * 4 + 2] += xi * w.z;
                    acc[j4 * 4 + 3] += xi * w.w;
                }
            }
        }
        __syncthreads();
    }

    // mean over total in-degree
    float dg = deg[t0 + e];
    dg = dg < 1.f ? 1.f : dg;
    float inv = 1.f / dg;
#pragma unroll
    for (int j = 0; j < 32; ++j) acc[j] *= inv;

    // fused root GEMM: stage this tile's own x rows, same inner loop
#pragma unroll
    for (int p = 0; p < 8; ++p) {
        int row = (t >> 5) + p * 8;
        int c4 = t & 31;
        *(float4*)(&Ss[row][c4 * 4]) = *(const float4*)(x + (long)(t0 + row) * DIM + c4 * 4);
    }
    __syncthreads();
    {
        const float4* Rr = (const float4*)root;
        for (int i = 0; i < DIM; ++i) {
            float xi = Ss[e][i];
            const float4* wrow = Rr + i * (DIM / 4) + (ob >> 2);
#pragma unroll
            for (int j4 = 0; j4 < 8; ++j4) {
                float4 w = wrow[j4];
                acc[j4 * 4 + 0] += xi * w.x;
                acc[j4 * 4 + 1] += xi * w.y;
                acc[j4 * 4 + 2] += xi * w.z;
                acc[j4 * 4 + 3] += xi * w.w;
            }
        }
    }

    // bias + activation + single write
    float4* op4 = (float4*)(out + (long)(t0 + e) * DIM + ob);
    const float4* b4 = (const float4*)(bias + ob);
#pragma unroll
    for (int j4 = 0; j4 < 8; ++j4) {
        float4 b = b4[j4];
        float4 v;
        v.x = acc[j4 * 4 + 0] + b.x;
        v.y = acc[j4 * 4 + 1] + b.y;
        v.z = acc[j4 * 4 + 2] + b.z;
        v.w = acc[j4 * 4 + 3] + b.w;
        if (act) { v.x = tanhf(v.x); v.y = tanhf(v.y); v.z = tanhf(v.z); v.w = tanhf(v.w); }
        op4[j4] = v;
    }
}

__global__ void k_rel(const float* __restrict__ rel, const float* __restrict__ wrel,
                      float* __restrict__ out, int nrows) {
    int idx = blockIdx.x * 256 + threadIdx.x;
    if (idx >= nrows * DIM) return;
    int j = idx >> 7, o = idx & 127;
    float s = 0.f;
    for (int i = 0; i < DIM; ++i) s += rel[j * DIM + i] * wrel[i * DIM + o];
    out[idx] = s;
}

extern "C" void kernel_launch(void* const* d_in, const int* in_sizes, int n_in,
                              void* d_out, int out_size, void* d_ws, size_t ws_size,
                              hipStream_t stream) {
    const int* edge_index = (const int*)d_in[0];
    const int* edge_type  = (const int*)d_in[1];
    const float* init_embed = (const float*)d_in[2];
    const float* init_rel   = (const float*)d_in[3];
    const float* w_rel      = (const float*)d_in[4];
    const float* comp1  = (const float*)d_in[5];
    const float* basis1 = (const float*)d_in[6];
    const float* root1  = (const float*)d_in[7];
    const float* bias1  = (const float*)d_in[8];
    const float* comp2  = (const float*)d_in[9];
    const float* basis2 = (const float*)d_in[10];
    const float* root2  = (const float*)d_in[11];
    const float* bias2  = (const float*)d_in[12];

    int E = in_sizes[1];
    const int* src = edge_index;
    const int* dst = edge_index + E;
    int relrows = in_sizes[3] / DIM;   // 40

    // workspace layout
    float* W1  = (float*)d_ws;                       // 20*128*128
    float* W2  = W1 + NREL * DIM * DIM;              // 20*128*128
    float* h   = W2 + NREL * DIM * DIM;              // 40000*128 (layer-1 out)
    float* deg = h + (long)NENT * DIM;               // 40000
    int* hist   = (int*)(deg + NENT);                // 12500
    int* offs   = hist + NBIN;                       // 12501
    int* cursor = offs + NBIN + 1;                   // 12500
    int* sorted = cursor + NBIN;                     // E

    float* outx = (float*)d_out;
    float* outr = outx + (long)NENT * DIM;

    hipMemsetAsync(hist, 0, NBIN * sizeof(int), stream);
    hipMemsetAsync(deg, 0, NENT * sizeof(float), stream);

    k_weights<<<(NREL * DIM * DIM + 255) / 256, 256, 0, stream>>>(comp1, basis1, comp2, basis2, W1, W2);
    k_hist<<<(E + 255) / 256, 256, 0, stream>>>(edge_type, dst, E, hist, deg);
    k_scan<<<1, 256, 0, stream>>>(hist, offs, cursor);
    k_scatter<<<(E + 255) / 256, 256, 0, stream>>>(edge_type, dst, E, cursor, sorted);

    // layer 1: h = tanh(S@W1/deg + x@root1 + bias1)
    k_rgcn_tile<<<NTILE, 256, 0, stream>>>(init_embed, W1, root1, bias1,
                                           sorted, offs, src, dst, deg, h, 1);
    // layer 2: out = S@W2/deg + h@root2 + bias2
    k_rgcn_tile<<<NTILE, 256, 0, stream>>>(h, W2, root2, bias2,
                                           sorted, offs, src, dst, deg, outx, 0);

    // relation output: r = init_rel @ w_rel
    k_rel<<<(relrows * DIM + 255) / 256, 256, 0, stream>>>(init_rel, w_rel, outr, relrows);
}

// Round 3
// 1769.380 us; speedup vs baseline: 8.1680x; 8.1680x over previous
//
#include <hip/hip_runtime.h>
#include <hip/hip_bf16.h>

#define NENT 40000
#define NREL 20
#define DIM 128
#define NBASIS 8
#define NTILE 625              // 40000 / 64 dst-tiles
#define NBIN (NREL * NTILE)    // 12500 (rel, dst-tile) bins
#define SFP 132                // Sf row stride (f32): 2-way bank alias only
#define WTP 136                // W^T row stride (bf16): rows collide 2-way (free)

typedef __attribute__((ext_vector_type(8))) short sh8;
typedef __attribute__((ext_vector_type(4))) float fx4;

__device__ __forceinline__ short f2bf(float f) {
    union { __hip_bfloat16 h; short s; } u;
    u.h = __float2bfloat16(f);
    return u.s;
}

__device__ __forceinline__ void gl_lds16(const void* g, void* l) {
    __builtin_amdgcn_global_load_lds(
        (const __attribute__((address_space(1))) void*)g,
        (__attribute__((address_space(3))) void*)l, 16, 0, 0);
}

// W^T[r][o][i] (bf16, padded WTP) = sum_b comp[r,b]*basis[b,i,o]; also root^T.
__global__ void k_weights(const float* __restrict__ comp1, const float* __restrict__ basis1,
                          const float* __restrict__ comp2, const float* __restrict__ basis2,
                          const float* __restrict__ root1, const float* __restrict__ root2,
                          short* __restrict__ Wbt1, short* __restrict__ Wbt2,
                          short* __restrict__ rbt1, short* __restrict__ rbt2) {
    int idx = blockIdx.x * 256 + threadIdx.x;
    if (idx >= NREL * DIM * DIM) return;
    int r = idx >> 14;
    int rem = idx & 16383;
    int o = rem >> 7, i = rem & 127;
    float s1 = 0.f, s2 = 0.f;
#pragma unroll
    for (int b = 0; b < NBASIS; ++b) {
        float c1 = comp1[r * NBASIS + b], c2 = comp2[r * NBASIS + b];
        float bv1 = basis1[b * 16384 + i * 128 + o];
        float bv2 = basis2[b * 16384 + i * 128 + o];
        s1 += c1 * bv1;
        s2 += c2 * bv2;
    }
    size_t w = (size_t)r * 128 * WTP + o * WTP + i;
    Wbt1[w] = f2bf(s1);
    Wbt2[w] = f2bf(s2);
    if (r == 0) {
        rbt1[o * WTP + i] = f2bf(root1[i * 128 + o]);
        rbt2[o * WTP + i] = f2bf(root2[i * 128 + o]);
    }
}

__global__ void k_hist(const int* __restrict__ et, const int* __restrict__ dst, int E,
                       int* __restrict__ hist, float* __restrict__ deg) {
    int e = blockIdx.x * 256 + threadIdx.x;
    if (e >= E) return;
    int d = dst[e];
    atomicAdd(&hist[et[e] * NTILE + (d >> 6)], 1);
    atomicAdd(&deg[d], 1.0f);
}

__global__ void k_scan(const int* __restrict__ hist, int* __restrict__ offs,
                       int* __restrict__ cursor) {
    __shared__ int ps[256];
    int t = threadIdx.x;
    const int chunk = (NBIN + 255) / 256;   // 49
    int lo = t * chunk, hi = min(NBIN, lo + chunk);
    int s = 0;
    for (int i = lo; i < hi; ++i) s += hist[i];
    ps[t] = s;
    __syncthreads();
    for (int off = 1; off < 256; off <<= 1) {
        int v = (t >= off) ? ps[t - off] : 0;
        __syncthreads();
        ps[t] += v;
        __syncthreads();
    }
    int run = (t == 0) ? 0 : ps[t - 1];
    for (int i = lo; i < hi; ++i) {
        offs[i] = run;
        cursor[i] = run;
        run += hist[i];
    }
    if (t == 255) offs[NBIN] = run;
}

// counting-sort scatter: packed (src | dst_local<<16) per slot. src < 2^16.
__global__ void k_scatter(const int* __restrict__ et, const int* __restrict__ srcA,
                          const int* __restrict__ dstA, int E,
                          int* __restrict__ cursor, unsigned* __restrict__ packed) {
    int e = blockIdx.x * 256 + threadIdx.x;
    if (e >= E) return;
    int d = dstA[e];
    int bin = et[e] * NTILE + (d >> 6);
    int pos = atomicAdd(&cursor[bin], 1);
    packed[pos] = (unsigned)srcA[e] | ((unsigned)(d & 63) << 16);
}

// frag build + 32 MFMA: acc[c] += S[16 rows] @ W (one wave = 16 rows x 128 cols)
__device__ __forceinline__ void mfma_phase(const float (*Sf)[SFP], const short* Wl,
                                           int wr0, int l15, int lhi, fx4* acc) {
    sh8 a[4];
#pragma unroll
    for (int kk = 0; kk < 4; ++kk) {
        const float* ap = &Sf[wr0 + l15][kk * 32 + lhi * 8];
        float4 lo = *(const float4*)ap;
        float4 hi = *(const float4*)(ap + 4);
        sh8 v;
        v[0] = f2bf(lo.x); v[1] = f2bf(lo.y); v[2] = f2bf(lo.z); v[3] = f2bf(lo.w);
        v[4] = f2bf(hi.x); v[5] = f2bf(hi.y); v[6] = f2bf(hi.z); v[7] = f2bf(hi.w);
        a[kk] = v;
    }
#pragma unroll
    for (int c = 0; c < 8; ++c) {
#pragma unroll
        for (int kk = 0; kk < 4; ++kk) {
            sh8 b = *(const sh8*)(Wl + (c * 16 + l15) * WTP + kk * 32 + lhi * 8);
            acc[c] = __builtin_amdgcn_mfma_f32_16x16x32_bf16(a[kk], b, acc[c], 0, 0, 0);
        }
    }
}

// Fused RGCN layer, MFMA edition. Block owns 64 dst rows; per relation:
// zero Sf -> (async-stage W^T into LDS || gather x[src] rows, 32 in flight)
// -> bf16 frags -> MFMA accumulate. Then /deg, root-GEMM via MFMA, bias, act.
__global__ __launch_bounds__(256) void k_rgcn_mfma(
    const float* __restrict__ x, const short* __restrict__ Wbt,
    const short* __restrict__ rootbt, const float* __restrict__ bias,
    const unsigned* __restrict__ packed, const int* __restrict__ offs,
    const float* __restrict__ deg, float* __restrict__ out, int act) {
    __shared__ __align__(16) float Sf[64][SFP];
    __shared__ __align__(16) short Wl[128 * WTP];

    int tile = blockIdx.x, t0 = tile * 64;
    int t = threadIdx.x;
    int lane = t & 63, wid = t >> 6;
    int wr0 = wid * 16;
    int l15 = lane & 15, lhi = lane >> 4;

    fx4 acc[8];
#pragma unroll
    for (int c = 0; c < 8; ++c) acc[c] = (fx4){0.f, 0.f, 0.f, 0.f};

    int g = t >> 5, c4 = t & 31;
    const float* xc = x + c4 * 4;

    for (int r = 0; r < NREL; ++r) {
        int beg = offs[r * NTILE + tile];
        int end = offs[r * NTILE + tile + 1];
        if (end == beg) continue;            // block-uniform

        // zero S tile [64][128]
#pragma unroll
        for (int p = 0; p < 8; ++p) {
            int rr = (t >> 5) + p * 8;
            *(float4*)(&Sf[rr][(t & 31) * 4]) = make_float4(0.f, 0.f, 0.f, 0.f);
        }
        __syncthreads();

        // async-stage W^T_r (34816 B) — overlaps with the gather below
        {
            const char* gsrc = (const char*)(Wbt + (size_t)r * 128 * WTP);
            char* ldst = (char*)Wl;
#pragma unroll
            for (int p = 0; p < 8; ++p) {
                int off = p * 4096 + wid * 1024;
                gl_lds16(gsrc + off + lane * 16, ldst + off);
            }
            if (t < 128) {
                int off = 8 * 4096 + wid * 1024;
                gl_lds16(gsrc + off + lane * 16, ldst + off);
            }
        }

        // gather: 8 groups x 4 unrolled = 32 rows in flight
        for (int ei = beg + g; ei < end; ei += 32) {
            int i2 = ei + 8, i3 = ei + 16, i4 = ei + 24;
            bool h2 = i2 < end, h3 = i3 < end, h4 = i4 < end;
            unsigned p1 = packed[ei];
            unsigned p2 = packed[h2 ? i2 : ei];
            unsigned p3 = packed[h3 ? i3 : ei];
            unsigned p4 = packed[h4 ? i4 : ei];
            float4 v1 = *(const float4*)(xc + (size_t)(p1 & 0xFFFFu) * DIM);
            float4 v2 = *(const float4*)(xc + (size_t)(p2 & 0xFFFFu) * DIM);
            float4 v3 = *(const float4*)(xc + (size_t)(p3 & 0xFFFFu) * DIM);
            float4 v4 = *(const float4*)(xc + (size_t)(p4 & 0xFFFFu) * DIM);
            float* s1 = &Sf[(p1 >> 16) & 63][c4 * 4];
            atomicAdd(s1 + 0, v1.x); atomicAdd(s1 + 1, v1.y);
            atomicAdd(s1 + 2, v1.z); atomicAdd(s1 + 3, v1.w);
            if (h2) {
                float* s2 = &Sf[(p2 >> 16) & 63][c4 * 4];
                atomicAdd(s2 + 0, v2.x); atomicAdd(s2 + 1, v2.y);
                atomicAdd(s2 + 2, v2.z); atomicAdd(s2 + 3, v2.w);
            }
            if (h3) {
                float* s3 = &Sf[(p3 >> 16) & 63][c4 * 4];
                atomicAdd(s3 + 0, v3.x); atomicAdd(s3 + 1, v3.y);
                atomicAdd(s3 + 2, v3.z); atomicAdd(s3 + 3, v3.w);
            }
            if (h4) {
                float* s4 = &Sf[(p4 >> 16) & 63][c4 * 4];
                atomicAdd(s4 + 0, v4.x); atomicAdd(s4 + 1, v4.y);
                atomicAdd(s4 + 2, v4.z); atomicAdd(s4 + 3, v4.w);
            }
        }
        __syncthreads();   // drains gather atomics AND the W^T async loads

        mfma_phase(Sf, Wl, wr0, l15, lhi, acc);
        __syncthreads();   // before next relation overwrites Sf/Wl
    }

    // mean over total in-degree (C/D row = lhi*4 + j)
    float invd[4];
#pragma unroll
    for (int j = 0; j < 4; ++j) {
        float dg = deg[t0 + wr0 + lhi * 4 + j];
        invd[j] = 1.f / (dg < 1.f ? 1.f : dg);
    }
#pragma unroll
    for (int c = 0; c < 8; ++c) {
#pragma unroll
        for (int j = 0; j < 4; ++j) acc[c][j] *= invd[j];
    }

    // root GEMM: stage this tile's x rows + root^T, same MFMA path
#pragma unroll
    for (int p = 0; p < 8; ++p) {
        int rr = (t >> 5) + p * 8;
        *(float4*)(&Sf[rr][(t & 31) * 4]) =
            *(const float4*)(x + (size_t)(t0 + rr) * DIM + (t & 31) * 4);
    }
    {
        const char* gsrc = (const char*)rootbt;
        char* ldst = (char*)Wl;
#pragma unroll
        for (int p = 0; p < 8; ++p) {
            int off = p * 4096 + wid * 1024;
            gl_lds16(gsrc + off + lane * 16, ldst + off);
        }
        if (t < 128) {
            int off = 8 * 4096 + wid * 1024;
            gl_lds16(gsrc + off + lane * 16, ldst + off);
        }
    }
    __syncthreads();
    mfma_phase(Sf, Wl, wr0, l15, lhi, acc);

    // bias + act + store (cols 16-contig per store: coalesced at line level)
#pragma unroll
    for (int c = 0; c < 8; ++c) {
        int col = c * 16 + l15;
        float bv = bias[col];
#pragma unroll
        for (int j = 0; j < 4; ++j) {
            float v = acc[c][j] + bv;
            if (act) v = tanhf(v);
            out[(size_t)(t0 + wr0 + lhi * 4 + j) * DIM + col] = v;
        }
    }
}

__global__ void k_rel(const float* __restrict__ rel, const float* __restrict__ wrel,
                      float* __restrict__ out, int nrows) {
    int idx = blockIdx.x * 256 + threadIdx.x;
    if (idx >= nrows * DIM) return;
    int j = idx >> 7, o = idx & 127;
    float s = 0.f;
    for (int i = 0; i < DIM; ++i) s += rel[j * DIM + i] * wrel[i * DIM + o];
    out[idx] = s;
}

extern "C" void kernel_launch(void* const* d_in, const int* in_sizes, int n_in,
                              void* d_out, int out_size, void* d_ws, size_t ws_size,
                              hipStream_t stream) {
    const int* edge_index = (const int*)d_in[0];
    const int* edge_type  = (const int*)d_in[1];
    const float* init_embed = (const float*)d_in[2];
    const float* init_rel   = (const float*)d_in[3];
    const float* w_rel      = (const float*)d_in[4];
    const float* comp1  = (const float*)d_in[5];
    const float* basis1 = (const float*)d_in[6];
    const float* root1  = (const float*)d_in[7];
    const float* bias1  = (const float*)d_in[8];
    const float* comp2  = (const float*)d_in[9];
    const float* basis2 = (const float*)d_in[10];
    const float* root2  = (const float*)d_in[11];
    const float* bias2  = (const float*)d_in[12];

    int E = in_sizes[1];
    const int* src = edge_index;
    const int* dst = edge_index + E;
    int relrows = in_sizes[3] / DIM;   // 40

    // workspace layout (16B-aligned regions)
    short* Wbt1 = (short*)d_ws;                          // 20*128*136
    short* Wbt2 = Wbt1 + (size_t)NREL * 128 * WTP;
    short* rbt1 = Wbt2 + (size_t)NREL * 128 * WTP;       // 128*136
    short* rbt2 = rbt1 + 128 * WTP;
    float* h    = (float*)(rbt2 + 128 * WTP);            // 40000*128
    float* deg  = h + (size_t)NENT * DIM;                // 40000
    int* hist     = (int*)(deg + NENT);                  // pad to 12512
    int* offs     = hist + 12512;
    int* cursor   = offs + 12512;
    unsigned* packed = (unsigned*)(cursor + 12512);      // E

    float* outx = (float*)d_out;
    float* outr = outx + (size_t)NENT * DIM;

    hipMemsetAsync(hist, 0, NBIN * sizeof(int), stream);
    hipMemsetAsync(deg, 0, NENT * sizeof(float), stream);

    k_weights<<<(NREL * DIM * DIM + 255) / 256, 256, 0, stream>>>(
        comp1, basis1, comp2, basis2, root1, root2, Wbt1, Wbt2, rbt1, rbt2);
    k_hist<<<(E + 255) / 256, 256, 0, stream>>>(edge_type, dst, E, hist, deg);
    k_scan<<<1, 256, 0, stream>>>(hist, offs, cursor);
    k_scatter<<<(E + 255) / 256, 256, 0, stream>>>(edge_type, src, dst, E, cursor, packed);

    // layer 1: h = tanh(S@W1/deg + x@root1 + bias1)
    k_rgcn_mfma<<<NTILE, 256, 0, stream>>>(init_embed, Wbt1, rbt1, bias1,
                                           packed, offs, deg, h, 1);
    // layer 2: out = S@W2/deg + h@root2 + bias2
    k_rgcn_mfma<<<NTILE, 256, 0, stream>>>(h, Wbt2, rbt2, bias2,
                                           packed, offs, deg, outx, 0);

    // relation output: r = init_rel @ w_rel
    k_rel<<<(relrows * DIM + 255) / 256, 256, 0, stream>>>(init_rel, w_rel, outr, relrows);
}

// Round 4
// 1336.992 us; speedup vs baseline: 10.8096x; 1.3234x over previous
//
#include <hip/hip_runtime.h>
#include <hip/hip_bf16.h>

#define NENT 40000
#define NREL 20
#define DIM 128
#define NBASIS 8
#define NTILE 625              // 40000 / 64 dst-tiles
#define NBIN (NREL * NTILE)    // 12500 (rel, dst-tile) bins
#define SFP 132                // Sf row stride (f32)

typedef __attribute__((ext_vector_type(8))) short sh8;
typedef __attribute__((ext_vector_type(4))) float fx4;

__device__ __forceinline__ short f2bf(float f) {
    union { __hip_bfloat16 h; short s; } u;
    u.h = __float2bfloat16(f);
    return u.s;
}

// Fragment-order weights: Wf[r][c][kk][lane] = sh8 holding
// W^T[r][col][i..i+7] with col = c*16 + (lane&15), i = kk*32 + (lane>>4)*8.
// One thread per (i,o); reads basis coalesced in o, computes all 20 relations.
__global__ void k_wfrag(const float* __restrict__ comp, const float* __restrict__ basis,
                        const float* __restrict__ root,
                        short* __restrict__ Wf, short* __restrict__ rf) {
    int t = blockIdx.x * 256 + threadIdx.x;
    if (t >= DIM * DIM) return;
    int i = t >> 7, o = t & 127;
    float bv[NBASIS];
#pragma unroll
    for (int b = 0; b < NBASIS; ++b) bv[b] = basis[b * 16384 + i * 128 + o];
    int c = o >> 4, l15 = o & 15;
    int kk = i >> 5, lhi = (i >> 3) & 3, e = i & 7;
    int lane = l15 + lhi * 16;
    size_t base = (((size_t)c * 4 + kk) * 64 + lane) * 8 + e;
#pragma unroll
    for (int r = 0; r < NREL; ++r) {
        float s = 0.f;
#pragma unroll
        for (int b = 0; b < NBASIS; ++b) s += comp[r * NBASIS + b] * bv[b];
        Wf[(size_t)r * 16384 + base] = f2bf(s);
    }
    rf[base] = f2bf(root[i * 128 + o]);
}

__global__ void k_hist(const int* __restrict__ et, const int* __restrict__ dst, int E,
                       int* __restrict__ hist, float* __restrict__ deg) {
    int e = blockIdx.x * 256 + threadIdx.x;
    if (e >= E) return;
    int d = dst[e];
    atomicAdd(&hist[et[e] * NTILE + (d >> 6)], 1);
    atomicAdd(&deg[d], 1.0f);
}

__global__ void k_scan(const int* __restrict__ hist, int* __restrict__ offs,
                       int* __restrict__ cursor) {
    __shared__ int ps[256];
    int t = threadIdx.x;
    const int chunk = (NBIN + 255) / 256;
    int lo = t * chunk, hi = min(NBIN, lo + chunk);
    int s = 0;
    for (int i = lo; i < hi; ++i) s += hist[i];
    ps[t] = s;
    __syncthreads();
    for (int off = 1; off < 256; off <<= 1) {
        int v = (t >= off) ? ps[t - off] : 0;
        __syncthreads();
        ps[t] += v;
        __syncthreads();
    }
    int run = (t == 0) ? 0 : ps[t - 1];
    for (int i = lo; i < hi; ++i) {
        offs[i] = run;
        cursor[i] = run;
        run += hist[i];
    }
    if (t == 255) offs[NBIN] = run;
}

__global__ void k_scatter(const int* __restrict__ et, const int* __restrict__ srcA,
                          const int* __restrict__ dstA, int E,
                          int* __restrict__ cursor, unsigned* __restrict__ packed) {
    int e = blockIdx.x * 256 + threadIdx.x;
    if (e >= E) return;
    int d = dstA[e];
    int bin = et[e] * NTILE + (d >> 6);
    int pos = atomicAdd(&cursor[bin], 1);
    packed[pos] = (unsigned)srcA[e] | ((unsigned)(d & 63) << 16);
}

// gather one relation's edges into buf: 8 groups x unroll 8 = 64 rows in flight
__device__ __forceinline__ void gather_rel(const unsigned* __restrict__ packed,
                                           int beg, int end, const float* __restrict__ xc,
                                           int g, int c4, float (*buf)[SFP]) {
    for (int ei = beg + g; ei < end; ei += 64) {
        unsigned pk[8];
        float4 v[8];
#pragma unroll
        for (int u = 0; u < 8; ++u) {
            int i = ei + u * 8;
            pk[u] = packed[i < end ? i : ei];
        }
#pragma unroll
        for (int u = 0; u < 8; ++u)
            v[u] = *(const float4*)(xc + (size_t)(pk[u] & 0xFFFFu) * DIM);
#pragma unroll
        for (int u = 0; u < 8; ++u) {
            int i = ei + u * 8;
            if (i < end) {
                float* s = &buf[(pk[u] >> 16) & 63][c4 * 4];
                atomicAdd(s + 0, v[u].x);
                atomicAdd(s + 1, v[u].y);
                atomicAdd(s + 2, v[u].z);
                atomicAdd(s + 3, v[u].w);
            }
        }
    }
}

// read A-frags from S and write zeros back (each element read exactly once)
__device__ __forceinline__ void afrag_rdzero(float (*S)[SFP], int wr0, int l15, int lhi,
                                             sh8* a) {
    const float4 z = make_float4(0.f, 0.f, 0.f, 0.f);
#pragma unroll
    for (int kk = 0; kk < 4; ++kk) {
        float* ap = &S[wr0 + l15][kk * 32 + lhi * 8];
        float4 lo = *(float4*)ap;
        float4 hi = *(float4*)(ap + 4);
        *(float4*)ap = z;
        *(float4*)(ap + 4) = z;
        sh8 vv;
        vv[0] = f2bf(lo.x); vv[1] = f2bf(lo.y); vv[2] = f2bf(lo.z); vv[3] = f2bf(lo.w);
        vv[4] = f2bf(hi.x); vv[5] = f2bf(hi.y); vv[6] = f2bf(hi.z); vv[7] = f2bf(hi.w);
        a[kk] = vv;
    }
}

__device__ __forceinline__ void afrag_rd(const float (*S)[SFP], int wr0, int l15, int lhi,
                                         sh8* a) {
#pragma unroll
    for (int kk = 0; kk < 4; ++kk) {
        const float* ap = &S[wr0 + l15][kk * 32 + lhi * 8];
        float4 lo = *(const float4*)ap;
        float4 hi = *(const float4*)(ap + 4);
        sh8 vv;
        vv[0] = f2bf(lo.x); vv[1] = f2bf(lo.y); vv[2] = f2bf(lo.z); vv[3] = f2bf(lo.w);
        vv[4] = f2bf(hi.x); vv[5] = f2bf(hi.y); vv[6] = f2bf(hi.z); vv[7] = f2bf(hi.w);
        a[kk] = vv;
    }
}

// Fused RGCN layer: double-buffered Sf, 1 barrier/relation.
// gather(r+1)->buf[nxt] overlaps MFMA(r) on buf[cur]; B-frags straight from
// global in fragment order (coalesced, no LDS).
__global__ __launch_bounds__(256) void k_rgcn_mfma(
    const float* __restrict__ x, const short* __restrict__ Wf,
    const short* __restrict__ rf, const float* __restrict__ bias,
    const unsigned* __restrict__ packed, const int* __restrict__ offs,
    const float* __restrict__ deg, float* __restrict__ out, int act) {
    __shared__ __align__(16) float Sf[2][64][SFP];

    int tile = blockIdx.x, t0 = tile * 64;
    int t = threadIdx.x;
    int lane = t & 63, wid = t >> 6, wr0 = wid * 16;
    int l15 = lane & 15, lhi = lane >> 4;
    int g = t >> 5, c4 = t & 31;
    const float* xc = x + c4 * 4;

    fx4 acc[8];
#pragma unroll
    for (int c = 0; c < 8; ++c) acc[c] = (fx4){0.f, 0.f, 0.f, 0.f};

    // zero both buffers once
    {
        const float4 z = make_float4(0.f, 0.f, 0.f, 0.f);
        float4* p = (float4*)&Sf[0][0][0];
        for (int i = t; i < 2 * 64 * SFP / 4; i += 256) p[i] = z;
    }
    __syncthreads();
    gather_rel(packed, offs[tile], offs[tile + 1], xc, g, c4, Sf[0]);

    for (int r = 0; r < NREL; ++r) {
        __syncthreads();   // gather(r) done; mfma(r-1) done (its buffer zeroed)
        float (*cur)[SFP] = Sf[r & 1];
        float (*nxt)[SFP] = Sf[(r & 1) ^ 1];
        if (r + 1 < NREL)
            gather_rel(packed, offs[(r + 1) * NTILE + tile],
                       offs[(r + 1) * NTILE + tile + 1], xc, g, c4, nxt);

        sh8 a[4];
        afrag_rdzero(cur, wr0, l15, lhi, a);
        const sh8* W8 = (const sh8*)(Wf + (size_t)r * 16384);
#pragma unroll
        for (int c = 0; c < 8; ++c) {
#pragma unroll
            for (int kk = 0; kk < 4; ++kk) {
                sh8 b = W8[(c * 4 + kk) * 64 + lane];
                acc[c] = __builtin_amdgcn_mfma_f32_16x16x32_bf16(a[kk], b, acc[c], 0, 0, 0);
            }
        }
    }

    // mean over in-degree (C/D row = lhi*4 + j)
    float invd[4];
#pragma unroll
    for (int j = 0; j < 4; ++j) {
        float dg = deg[t0 + wr0 + lhi * 4 + j];
        invd[j] = 1.f / (dg < 1.f ? 1.f : dg);
    }
#pragma unroll
    for (int c = 0; c < 8; ++c)
#pragma unroll
        for (int j = 0; j < 4; ++j) acc[c][j] *= invd[j];

    // root GEMM: stage own x rows into Sf[0] (free+zero after r=18), frags from rf
    {
        float (*S0)[SFP] = Sf[0];
#pragma unroll
        for (int p = 0; p < 8; ++p) {
            int rr = g + p * 8;
            *(float4*)(&S0[rr][c4 * 4]) =
                *(const float4*)(x + (size_t)(t0 + rr) * DIM + c4 * 4);
        }
        __syncthreads();
        sh8 a[4];
        afrag_rd(S0, wr0, l15, lhi, a);
        const sh8* R8 = (const sh8*)rf;
#pragma unroll
        for (int c = 0; c < 8; ++c) {
#pragma unroll
            for (int kk = 0; kk < 4; ++kk) {
                sh8 b = R8[(c * 4 + kk) * 64 + lane];
                acc[c] = __builtin_amdgcn_mfma_f32_16x16x32_bf16(a[kk], b, acc[c], 0, 0, 0);
            }
        }
    }

    // bias + act + store
#pragma unroll
    for (int c = 0; c < 8; ++c) {
        int col = c * 16 + l15;
        float bv = bias[col];
#pragma unroll
        for (int j = 0; j < 4; ++j) {
            float v = acc[c][j] + bv;
            if (act) v = tanhf(v);
            out[(size_t)(t0 + wr0 + lhi * 4 + j) * DIM + col] = v;
        }
    }
}

__global__ void k_rel(const float* __restrict__ rel, const float* __restrict__ wrel,
                      float* __restrict__ out, int nrows) {
    int idx = blockIdx.x * 256 + threadIdx.x;
    if (idx >= nrows * DIM) return;
    int j = idx >> 7, o = idx & 127;
    float s = 0.f;
    for (int i = 0; i < DIM; ++i) s += rel[j * DIM + i] * wrel[i * DIM + o];
    out[idx] = s;
}

extern "C" void kernel_launch(void* const* d_in, const int* in_sizes, int n_in,
                              void* d_out, int out_size, void* d_ws, size_t ws_size,
                              hipStream_t stream) {
    const int* edge_index = (const int*)d_in[0];
    const int* edge_type  = (const int*)d_in[1];
    const float* init_embed = (const float*)d_in[2];
    const float* init_rel   = (const float*)d_in[3];
    const float* w_rel      = (const float*)d_in[4];
    const float* comp1  = (const float*)d_in[5];
    const float* basis1 = (const float*)d_in[6];
    const float* root1  = (const float*)d_in[7];
    const float* bias1  = (const float*)d_in[8];
    const float* comp2  = (const float*)d_in[9];
    const float* basis2 = (const float*)d_in[10];
    const float* root2  = (const float*)d_in[11];
    const float* bias2  = (const float*)d_in[12];

    int E = in_sizes[1];
    const int* src = edge_index;
    const int* dst = edge_index + E;
    int relrows = in_sizes[3] / DIM;   // 40

    // workspace layout (16B-aligned regions)
    short* Wf1 = (short*)d_ws;                           // 20*16384 shorts
    short* Wf2 = Wf1 + (size_t)NREL * 16384;
    short* rf1 = Wf2 + (size_t)NREL * 16384;             // 16384
    short* rf2 = rf1 + 16384;
    float* h   = (float*)(rf2 + 16384);                  // 40000*128
    float* deg = h + (size_t)NENT * DIM;                 // 40000
    int* hist     = (int*)(deg + NENT);                  // pad 12512
    int* offs     = hist + 12512;
    int* cursor   = offs + 12512;
    unsigned* packed = (unsigned*)(cursor + 12512);      // E

    float* outx = (float*)d_out;
    float* outr = outx + (size_t)NENT * DIM;

    hipMemsetAsync(hist, 0, NBIN * sizeof(int), stream);
    hipMemsetAsync(deg, 0, NENT * sizeof(float), stream);

    k_wfrag<<<64, 256, 0, stream>>>(comp1, basis1, root1, Wf1, rf1);
    k_wfrag<<<64, 256, 0, stream>>>(comp2, basis2, root2, Wf2, rf2);
    k_hist<<<(E + 255) / 256, 256, 0, stream>>>(edge_type, dst, E, hist, deg);
    k_scan<<<1, 256, 0, stream>>>(hist, offs, cursor);
    k_scatter<<<(E + 255) / 256, 256, 0, stream>>>(edge_type, src, dst, E, cursor, packed);

    // layer 1: h = tanh(S@W1/deg + x@root1 + bias1)
    k_rgcn_mfma<<<NTILE, 256, 0, stream>>>(init_embed, Wf1, rf1, bias1,
                                           packed, offs, deg, h, 1);
    // layer 2: out = S@W2/deg + h@root2 + bias2
    k_rgcn_mfma<<<NTILE, 256, 0, stream>>>(h, Wf2, rf2, bias2,
                                           packed, offs, deg, outx, 0);

    // relation output: r = init_rel @ w_rel
    k_rel<<<(relrows * DIM + 255) / 256, 256, 0, stream>>>(init_rel, w_rel, outr, relrows);
}